// Round 16
// baseline (1325.836 us; speedup 1.0000x reference)
//
#include <hip/hip_runtime.h>
#include <math.h>

#define N_OBJ   2048
#define R_REL   1024
#define OBJ_DIM 4096
#define H       512
#define NREL    51
#define NCLS    151
#define NODE    53
#define CLS_K   (NODE*H)       /* 27136 */
#define AST     512

typedef unsigned short u16;
typedef unsigned int   u32;
typedef __attribute__((ext_vector_type(8))) short bf16x8;
typedef __attribute__((ext_vector_type(4))) float f32x4;
typedef __attribute__((ext_vector_type(4))) unsigned int u32x4;

__device__ __forceinline__ float sigmoidf_(float x){ return 1.0f/(1.0f+__expf(-x)); }
__device__ __forceinline__ float tanhf_(float x){ float e = __expf(2.0f*x); return 1.0f - 2.0f/(e+1.0f); }
__device__ __forceinline__ u16 f2bf(float x){
  unsigned u = __float_as_uint(x);
  unsigned r = (u + 0x7fffu + ((u>>16)&1u)) >> 16;
  return (u16)r;
}
__device__ __forceinline__ float bf2f(u16 h){ return __uint_as_float(((unsigned)h)<<16); }

#define GLL16(gp, lp) __builtin_amdgcn_global_load_lds( \
    (const __attribute__((address_space(1))) void*)(gp), \
    (__attribute__((address_space(3))) void*)(lp), 16, 0, 0)

struct EpiArgs {
  u16* cbf;     // bf16 output
};

// C[m,n] = sum_k A[m,k]*B[n,k] (+bias[n]) -> bf16 cbf. BM=BN=128, BK=32, 2-phase gll pipeline.
__global__ __launch_bounds__(256)
void gemm_bf16(const u16* __restrict__ A, int lda,
               const u16* __restrict__ B, int ldb,
               const float* __restrict__ bias,
               int ldc, int K, EpiArgs e)
{
  __shared__ __align__(16) u16 As[2][128*32];
  __shared__ __align__(16) u16 Bs[2][128*32];
  const int tid = threadIdx.x;
  const int l   = tid & 63;
  const int w   = tid >> 6;
  const int wm  = w >> 1, wn = w & 1;
  const int bm  = blockIdx.y*128, bn = blockIdx.x*128;
  const int lr  = l & 15, q = l >> 4;

  const int srow = w*32 + (l >> 2);
  const int scol = (l & 3)*8;
  const u16* gA = A + (size_t)(bm + srow)*lda + scol;
  const u16* gB = B + (size_t)(bn + srow)*ldb + scol;
  const size_t a16 = (size_t)16*lda, b16 = (size_t)16*ldb;

  f32x4 acc[4][4] = {};
  const int NT = K >> 5;

  {
    GLL16(gA,       &As[0][(w*32     )*32]);
    GLL16(gA + a16, &As[0][(w*32 + 16)*32]);
    GLL16(gB,       &Bs[0][(w*32     )*32]);
    GLL16(gB + b16, &Bs[0][(w*32 + 16)*32]);
  }
  __syncthreads();
  int cur = 0;
  for (int kt = 0; kt < NT; ++kt){
    if (kt + 1 < NT){
      const u16* ga = gA + (size_t)(kt+1)*32;
      const u16* gb = gB + (size_t)(kt+1)*32;
      const int nb = cur ^ 1;
      GLL16(ga,       &As[nb][(w*32     )*32]);
      GLL16(ga + a16, &As[nb][(w*32 + 16)*32]);
      GLL16(gb,       &Bs[nb][(w*32     )*32]);
      GLL16(gb + b16, &Bs[nb][(w*32 + 16)*32]);
    }
    bf16x8 af[4], bfr[4];
#pragma unroll
    for (int i = 0; i < 4; ++i)
      af[i] = *(const bf16x8*)&As[cur][(wm*64 + i*16 + lr)*32 + q*8];
#pragma unroll
    for (int i = 0; i < 4; ++i)
      bfr[i] = *(const bf16x8*)&Bs[cur][(wn*64 + i*16 + lr)*32 + q*8];
#pragma unroll
    for (int mi = 0; mi < 4; ++mi)
#pragma unroll
      for (int ni = 0; ni < 4; ++ni)
        acc[mi][ni] = __builtin_amdgcn_mfma_f32_16x16x32_bf16(af[mi], bfr[ni], acc[mi][ni], 0, 0, 0);
    __syncthreads();
    cur ^= 1;
  }

#pragma unroll
  for (int mi = 0; mi < 4; ++mi)
#pragma unroll
    for (int ni = 0; ni < 4; ++ni)
#pragma unroll
      for (int i = 0; i < 4; ++i){
        const int m = bm + wm*64 + mi*16 + q*4 + i;
        const int n = bn + wn*64 + ni*16 + lr;
        float val = acc[mi][ni][i];
        if (bias) val += bias[n];
        e.cbf[(size_t)m*ldc + n] = f2bf(val);
      }
}

// ---------------- fused GGNN GRU step ----------------
// 64-row flat tile, 1024 threads = 16 waves (1 x 16 grid): wave = 64 rows x 32 cols.
// Halves B panel traffic (848 blocks) and doubles TLP (4 waves/SIMD) vs the r15 kernel.
// flat kept in packed regs through GEMM2 -> no Rv buffer; rvf/h' overwrite Afl.
struct FArgs {
  u16* hid;              // [M][512] bf16, in-place updated
  const u16* of;         // [2048][512]
  const u16* v;          // [1024][512]
  const int* ri;
  const u16* U3;         // [512][512]
  const u16* U5;
  const u16* ow1;
  const float* u3b; const float* u5b;
  const float* b3; const float* b4; const float* b5;
  const float* outbias;
  const float* Arel;     // [R_REL][51]
  const u16* msW;        // [2*RC][1536] bf16
  const u16* ofW2b;      // [2048][512] bf16
  const u16* vW2b;       // [1024][512] bf16
  u16* act;              // [M][512] bf16 (STEP2 output; may alias hid)
  int rbase; int RCc;
};

#define SWZ(m_, n_) ((m_)*AST + ((((((n_)>>3)) ^ ((m_)&7))<<3) | ((n_)&7)))

template<int STEP>   // 0: gather-staged first step; 1: middle; 2: last + out-layer
__global__ __launch_bounds__(1024)
__attribute__((amdgpu_flat_work_group_size(1024,1024)))
__attribute__((amdgpu_waves_per_eu(4,4)))
void ggnn_step(FArgs a)
{
  __shared__ __align__(16) u16 Afl[64*AST];     // flat / rvf / h'  (64 KB)
  __shared__ __align__(16) u16 Bw[16*2*1024];   // per-wave B double buffers (64 KB)
  __shared__ __align__(16) u16 SmsW[6*1536];    // up to 3 relations x {top,bot} (18 KB)
  __shared__ float SArel[3*51];
  const int tid = threadIdx.x;
  const int w = tid >> 6, l = tid & 63;         // 16 waves
  const int lr = l & 15, q = l >> 4;
  const int gm0 = blockIdx.x * 64;
  const int rblk0 = gm0 / 53;
  u16* myB = &Bw[w*2048];

  // ---- stage A (flat) rows into LDS (pre-swizzled source cols); 4 rows per wave
#pragma unroll
  for (int j = 0; j < 4; ++j){
    const int row = j*16 + w;
    const int gm = gm0 + row;
    const u16* src;
    if (STEP == 0){
      const int r = gm/53, t = gm - r*53, gr = a.rbase + r;
      src = (t==0) ? a.of + (size_t)a.ri[gr*3+1]*512
          : (t==1) ? a.of + (size_t)a.ri[gr*3+2]*512
          :          a.v  + (size_t)gr*512;
    } else {
      src = a.hid + (size_t)gm*512;
    }
    GLL16(src + ((l ^ (row&7))<<3), &Afl[row*AST]);
  }
  // ---- stage up to 3 relations' msW rows into LDS
  if (w < 6){
    const int rloc = w >> 1, half = w & 1;
    int rg = rblk0 + rloc; if (rg >= a.RCc) rg = a.RCc - 1;
    const u16* srcw = a.msW + (size_t)(half ? (a.RCc + rg) : rg) * 1536;
#pragma unroll
    for (int j = 0; j < 3; ++j)
      GLL16(srcw + j*512 + l*8, &SmsW[(rloc*2+half)*1536 + j*512]);
  }
  // ---- stage Arel rows
  if (tid < 153){
    const int rloc = tid / 51, k = tid - rloc*51;
    int rg = rblk0 + rloc; if (rg >= a.RCc) rg = a.RCc - 1;
    SArel[rloc*51 + k] = a.Arel[(size_t)(a.rbase + rg)*NREL + k];
  }
  __syncthreads();   // drains all staging (vmcnt clean for counted waits below)

  f32x4 acc[4][2];
#define ZERO_ACC() { \
  _Pragma("unroll") for (int x_=0;x_<4;++x_) _Pragma("unroll") for (int y_=0;y_<2;++y_) acc[x_][y_] = (f32x4)0.0f; }

// wave-private B slab staging (2 GLL16 = 32 rows x 32 cols), slot-swizzled source
#define STAGE_W(Bp, buf_, kt_) { \
  _Pragma("unroll") for (int j_=0;j_<2;++j_){ \
    const int row_ = w*32 + j_*16 + (l>>2); \
    GLL16((Bp) + (size_t)row_*512 + (kt_)*32 + (((l&3) ^ ((row_>>1)&3))<<3), \
          &myB[(buf_)*1024 + j_*512]); } }

// barrier-free pipelined K-loop: depth-2 prefetch, counted vmcnt (2 loads/slab)
#define RUN_GEMM(Ap, Bp) { \
  STAGE_W(Bp, 0, 0); \
  STAGE_W(Bp, 1, 1); \
  _Pragma("unroll 1") \
  for (int kt = 0; kt < 16; ++kt){ \
    if (kt < 15) { asm volatile("s_waitcnt vmcnt(2)" ::: "memory"); } \
    else         { asm volatile("s_waitcnt vmcnt(0)" ::: "memory"); } \
    __builtin_amdgcn_sched_barrier(0); \
    bf16x8 af_[4], bf_[2]; \
    _Pragma("unroll") for (int mi_=0;mi_<4;++mi_){ \
      const int row_ = mi_*16 + lr; \
      af_[mi_] = *(const bf16x8*)&(Ap)[row_*AST + (((kt*4+q) ^ (row_&7))<<3)]; } \
    _Pragma("unroll") for (int ni_=0;ni_<2;++ni_){ \
      const int lrow_ = ni_*16 + lr; \
      bf_[ni_] = *(const bf16x8*)&myB[(kt&1)*1024 + lrow_*32 + ((q ^ ((lrow_>>1)&3))<<3)]; } \
    asm volatile("s_waitcnt lgkmcnt(0)" ::: "memory"); \
    __builtin_amdgcn_sched_barrier(0); \
    if (kt + 2 < 16) STAGE_W(Bp, kt&1, kt+2); \
    _Pragma("unroll") for (int mi_=0;mi_<4;++mi_) \
      _Pragma("unroll") for (int ni_=0;ni_<2;++ni_) \
        acc[mi_][ni_] = __builtin_amdgcn_mfma_f32_16x16x32_bf16(af_[mi_], bf_[ni_], acc[mi_][ni_], 0, 0, 0); \
  } }

  // ---- GEMM1: flat @ U3^T (reads Afl)
  ZERO_ACC();
  RUN_GEMM(Afl, a.U3);
  __syncthreads();   // all Afl reads done before rvf overwrites

  // ---- epilogue 1: z, flat -> packed regs; rvf overwrites Afl
  float vb3[2], vb4[2], vu3[2];
#pragma unroll
  for (int ni=0;ni<2;++ni){
    const int n = w*32 + ni*16 + lr;
    vb3[ni]=a.b3[n]; vb4[ni]=a.b4[n]; vu3[ni]=a.u3b[n];
  }
  u32 z_pk[4][2][2] = {};
  u32 f_pk[4][2][2] = {};
#pragma unroll
  for (int mi=0;mi<4;++mi)
#pragma unroll
   for (int i=0;i<4;++i){
    const int m = mi*16 + q*4 + i;
    const int gm = gm0 + m;
    const int r = gm/53, t = gm - r*53;
    const int rloc = r - rblk0;
    const float aA = (t<2) ? 1.0f : SArel[rloc*51 + (t-2)];
    const u16* mrow = &SmsW[(rloc*2 + ((t<2)?0:1))*1536];
#pragma unroll
    for (int ni=0;ni<2;++ni){
      const int n = w*32 + ni*16 + lr;
      const float val = acc[mi][ni][i] + vu3[ni];
      const float z  = sigmoidf_(fmaf(aA, bf2f(mrow[n]),     vb3[ni]) + val);
      const float rv = sigmoidf_(fmaf(aA, bf2f(mrow[512+n]), vb4[ni]) + val);
      const int sidx = SWZ(m, n);
      const float fl = bf2f(Afl[sidx]);
      z_pk[mi][i>>1][ni] |= ((u32)f2bf(z))  << ((i&1)*16);
      f_pk[mi][i>>1][ni] |= ((u32)f2bf(fl)) << ((i&1)*16);
      Afl[sidx] = f2bf(rv*fl);
    }
   }
  __syncthreads();   // rvf complete in Afl before GEMM2 reads it

  // ---- GEMM2: rvf @ U5^T (reads Afl)
  ZERO_ACC();
  RUN_GEMM(Afl, a.U5);
  __syncthreads();   // all rvf reads done before h' overwrites

  float vu5[2], vb5[2];
#pragma unroll
  for (int ni=0;ni<2;++ni){
    const int n = w*32 + ni*16 + lr;
    vu5[ni]=a.u5b[n]; vb5[ni]=a.b5[n];
  }
#pragma unroll
  for (int mi=0;mi<4;++mi)
#pragma unroll
   for (int i=0;i<4;++i){
    const int m = mi*16 + q*4 + i;
    const int gm = gm0 + m;
    const int r = gm/53, t = gm - r*53;
    const int rloc = r - rblk0;
    const float aA = (t<2) ? 1.0f : SArel[rloc*51 + (t-2)];
    const u16* mrow = &SmsW[(rloc*2 + ((t<2)?0:1))*1536];
#pragma unroll
    for (int ni=0;ni<2;++ni){
      const int n = w*32 + ni*16 + lr;
      const float val = acc[mi][ni][i] + vu5[ni];
      const float hv = tanhf_(fmaf(aA, bf2f(mrow[1024+n]), vb5[ni]) + val);
      const float z  = bf2f((u16)(z_pk[mi][i>>1][ni] >> ((i&1)*16)));
      const float fl = bf2f((u16)(f_pk[mi][i>>1][ni] >> ((i&1)*16)));
      Afl[SWZ(m, n)] = f2bf((1.0f - z)*fl + z*hv);
    }
   }
  __syncthreads();   // h' complete in Afl

  if (STEP < 2){
#pragma unroll
    for (int it = 0; it < 4; ++it){
      const int s = it*1024 + tid;
      const int row = s >> 6, cc = s & 63;
      const u32x4 v4 = *(const u32x4*)&Afl[row*AST + ((cc ^ (row&7))<<3)];
      __builtin_nontemporal_store(v4, (u32x4*)&a.hid[(size_t)(gm0+row)*512 + (cc<<3)]);
    }
  } else {
    // ---- GEMM3: out = relu(h' @ ow1^T + gather + outbias)
    ZERO_ACC();
    RUN_GEMM(Afl, a.ow1);
    __syncthreads();   // all h' reads done before act overwrites
    float vob[2];
#pragma unroll
    for (int ni=0;ni<2;++ni) vob[ni] = a.outbias[w*32 + ni*16 + lr];
#pragma unroll
    for (int mi=0;mi<4;++mi)
#pragma unroll
     for (int i=0;i<4;++i){
      const int m = mi*16 + q*4 + i;
      const int gm = gm0 + m;
      const int r = gm/53, t = gm - r*53, gr = a.rbase + r;
      const u16* g = (t==0) ? a.ofW2b + (size_t)a.ri[gr*3+1]*512
                   : (t==1) ? a.ofW2b + (size_t)a.ri[gr*3+2]*512
                   :          a.vW2b  + (size_t)gr*512;
#pragma unroll
      for (int ni=0;ni<2;++ni){
        const int n = w*32 + ni*16 + lr;
        const float val = acc[mi][ni][i] + vob[ni] + bf2f(__builtin_nontemporal_load(&g[n]));
        Afl[SWZ(m, n)] = f2bf(fmaxf(val, 0.0f));
      }
     }
    __syncthreads();
#pragma unroll
    for (int it = 0; it < 4; ++it){
      const int s = it*1024 + tid;
      const int row = s >> 6, cc = s & 63;
      const u32x4 v4 = *(const u32x4*)&Afl[row*AST + ((cc ^ (row&7))<<3)];
      __builtin_nontemporal_store(v4, (u32x4*)&a.act[(size_t)(gm0+row)*512 + (cc<<3)]);
    }
  }
#undef RUN_GEMM
#undef STAGE_W
#undef ZERO_ACC
}

// classifier split-K
__global__ __launch_bounds__(64)
void cls_gemm(const u16* __restrict__ A, const u16* __restrict__ B,
              float* __restrict__ part, int RC)
{
  const int bm = blockIdx.x*64;
  const int kz = blockIdx.y;
  const int l  = threadIdx.x;
  const int lr = l & 15, q = l >> 4;
  f32x4 acc[4][4] = {};
  const size_t kbase = (size_t)kz*1696 + q*8;
  for (int kt = 0; kt < 53; ++kt){
    const size_t ko = kbase + (size_t)kt*32;
    bf16x8 af[4], bfr[4];
#pragma unroll
    for (int i = 0; i < 4; ++i)
      af[i] = *(const bf16x8*)&A[(size_t)(bm + i*16 + lr)*CLS_K + ko];
#pragma unroll
    for (int i = 0; i < 4; ++i)
      bfr[i] = *(const bf16x8*)&B[(size_t)(i*16 + lr)*CLS_K + ko];
#pragma unroll
    for (int mi = 0; mi < 4; ++mi)
#pragma unroll
      for (int ni = 0; ni < 4; ++ni)
        acc[mi][ni] = __builtin_amdgcn_mfma_f32_16x16x32_bf16(af[mi], bfr[ni], acc[mi][ni], 0, 0, 0);
  }
#pragma unroll
  for (int mi = 0; mi < 4; ++mi)
#pragma unroll
    for (int ni = 0; ni < 4; ++ni)
#pragma unroll
      for (int i = 0; i < 4; ++i){
        int m = bm + mi*16 + q*4 + i;
        int n = ni*16 + lr;
        part[((size_t)kz*RC + m)*64 + n] = acc[mi][ni][i];
      }
}

__global__ void cls_reduce(const float* __restrict__ part, const float* __restrict__ clsb,
                           float* __restrict__ rd, int r0, int RC)
{
  const int m = blockIdx.x;
  const int c = threadIdx.x;
  if (c < NREL){
    float s = clsb[c];
    for (int kz = 0; kz < 16; ++kz) s += part[((size_t)kz*RC + m)*64 + c];
    rd[(size_t)(r0 + m)*NREL + c] = s;
  }
}

__global__ void argmax_copy_kernel(const float* __restrict__ logits, float* __restrict__ out, int* __restrict__ preds)
{
  const int i = blockIdx.x;
  const int lane = threadIdx.x; // 64
  for (int c = lane; c < NCLS; c += 64)
    out[(size_t)i*NCLS + c] = logits[(size_t)i*NCLS + c];
  float bv = -INFINITY; int bi = 0x7fffffff;
  for (int c = 1 + lane; c < NCLS; c += 64){
    float x = logits[(size_t)i*NCLS + c];
    if (x > bv){ bv = x; bi = c; }
  }
  for (int off = 32; off; off >>= 1){
    float ov = __shfl_down(bv, off);
    int   oi = __shfl_down(bi, off);
    if (ov > bv || (ov == bv && oi < bi)){ bv = ov; bi = oi; }
  }
  if (lane == 0){
    preds[i] = bi;
    out[(size_t)N_OBJ*NCLS + i] = (float)bi;
  }
}

__global__ void conv_f2b(const float* __restrict__ s, u16* __restrict__ d, long n)
{
  for (long i = (long)blockIdx.x*blockDim.x + threadIdx.x; i < n; i += (long)gridDim.x*blockDim.x)
    d[i] = f2bf(s[i]);
}

__global__ void conv_ow(const float* __restrict__ src, u16* __restrict__ d1, u16* __restrict__ d2)
{
  for (int i = blockIdx.x*blockDim.x + threadIdx.x; i < 512*512; i += gridDim.x*blockDim.x){
    int r = i >> 9, c = i & 511;
    d1[i] = f2bf(src[(size_t)r*1024 + c]);
    d2[i] = f2bf(src[(size_t)r*1024 + 512 + c]);
  }
}

__global__ void conv_cls(const float* __restrict__ src, u16* __restrict__ dst)
{
  const long total = 64L*CLS_K;
  for (long i = (long)blockIdx.x*blockDim.x + threadIdx.x; i < total; i += (long)gridDim.x*blockDim.x){
    long r = i / CLS_K, c = i - r*CLS_K;
    dst[i] = (r < NREL) ? f2bf(src[(size_t)r*CLS_K + c]) : (u16)0;
  }
}

__global__ void wcat_kernel(const float* __restrict__ e3w, const float* __restrict__ e4w,
                            const float* __restrict__ e5w, u16* __restrict__ Wcat)
{
  const int total = 1536*512;
  for (int i = blockIdx.x*blockDim.x + threadIdx.x; i < total; i += gridDim.x*blockDim.x){
    int j = i >> 9, k = i & 511;
    int w = j >> 9, n = j & 511;
    const float* Wp = (w == 0) ? e3w : (w == 1) ? e4w : e5w;
    Wcat[i] = f2bf(Wp[(size_t)n*1024 + k] + Wp[(size_t)n*1024 + 512 + k]);
  }
}

__global__ void arel_kernel(const int* __restrict__ preds, const int* __restrict__ ri,
                            const float* __restrict__ prior, float* __restrict__ Arel)
{
  const int total = R_REL*NREL;
  for (int i = blockIdx.x*blockDim.x + threadIdx.x; i < total; i += gridDim.x*blockDim.x){
    int r = i/NREL, k = i - r*NREL;
    int sp = preds[ri[r*3+1]];
    int op = preds[ri[r*3+2]];
    Arel[i] = prior[((size_t)sp*NCLS + op)*NREL + k];
  }
}

// step-0 X: m_top = (sum_k A[r,k]) * v[r]; s = of[si]+of[oi]
__global__ void mtop0_kernel(const u16* __restrict__ of_bf, const u16* __restrict__ v_bf,
                             const int* __restrict__ ri, const float* __restrict__ Arel,
                             u16* __restrict__ X, int rbase, int RC)
{
  const int r = blockIdx.x;
  const int gr = rbase + r;
  float sA = 0.f;
  for (int k = 0; k < NREL; ++k) sA += Arel[(size_t)gr*NREL + k];
  const int si = ri[gr*3+1], oi = ri[gr*3+2];
  for (int h = threadIdx.x; h < H; h += blockDim.x){
    X[(size_t)r*H + h] = f2bf(sA * bf2f(v_bf[(size_t)gr*H + h]));
    X[(size_t)(RC + r)*H + h] = f2bf(bf2f(of_bf[(size_t)si*H + h]) + bf2f(of_bf[(size_t)oi*H + h]));
  }
}

// general X from bf16 hidden
__global__ void mtopg_kernel(const u16* __restrict__ hidden, const float* __restrict__ Arel,
                             u16* __restrict__ X, int rbase, int RC)
{
  const int r = blockIdx.x;
  for (int h = threadIdx.x; h < H; h += blockDim.x){
    const u16* basep = hidden + ((size_t)r*NODE + 2)*H + h;
    float acc = 0.f;
    for (int k = 0; k < NREL; ++k)
      acc = fmaf(Arel[(size_t)(rbase+r)*NREL + k], bf2f(basep[(size_t)k*H]), acc);
    X[(size_t)r*H + h] = f2bf(acc);
    X[(size_t)(RC + r)*H + h] = f2bf(bf2f(hidden[(size_t)(r*NODE)*H + h]) + bf2f(hidden[(size_t)(r*NODE+1)*H + h]));
  }
}

extern "C" void kernel_launch(void* const* d_in, const int* in_sizes, int n_in,
                              void* d_out, int out_size, void* d_ws, size_t ws_size,
                              hipStream_t stream)
{
  const float* obj_fmaps = (const float*)d_in[0];
  const float* obj_logits= (const float*)d_in[1];
  const int*   rel_inds  = (const int*)d_in[2];
  const float* vr        = (const float*)d_in[3];
  const float* prior     = (const float*)d_in[4];
  const float* obj_proj_w= (const float*)d_in[5];
  const float* obj_proj_b= (const float*)d_in[6];
  const float* rel_proj_w= (const float*)d_in[7];
  const float* rel_proj_b= (const float*)d_in[8];
  const float* e3w =(const float*)d_in[9];
  const float* e3wb=(const float*)d_in[10];
  const float* e3u =(const float*)d_in[11];
  const float* e3ub=(const float*)d_in[12];
  const float* e4w =(const float*)d_in[13];
  const float* e4wb=(const float*)d_in[14];
  const float* e5w =(const float*)d_in[15];
  const float* e5wb=(const float*)d_in[16];
  const float* e5u =(const float*)d_in[17];
  const float* e5ub=(const float*)d_in[18];
  const float* outw=(const float*)d_in[19];
  const float* outbias=(const float*)d_in[20];
  const float* clsw=(const float*)d_in[21];
  const float* clsb=(const float*)d_in[22];
  float* out = (float*)d_out;
  (void)in_sizes; (void)n_in; (void)out_size;

  char* base = (char*)d_ws;
  size_t off = 0;
  auto take = [&](size_t bytes)->void*{
    void* p = base + off; off = (off + bytes + 63) & ~(size_t)63; return p;
  };
  // persistent (~21 MB)
  float* Arel   = (float*)take((size_t)R_REL*NREL*4);
  int*   preds  = (int*)take((size_t)N_OBJ*4);
  u16* opw_bf   = (u16*)take((size_t)H*OBJ_DIM*2);
  u16* rpw_bf   = (u16*)take((size_t)H*OBJ_DIM*2);
  u16* e3u_bf   = (u16*)take((size_t)H*H*2);
  u16* e5u_bf   = (u16*)take((size_t)H*H*2);
  u16* ow1_bf   = (u16*)take((size_t)H*H*2);
  u16* ow2_bf   = (u16*)take((size_t)H*H*2);
  u16* wcat_bf  = (u16*)take((size_t)1536*H*2);
  u16* clsw_bf  = (u16*)take((size_t)64*CLS_K*2);
  u16* of_bf    = (u16*)take((size_t)N_OBJ*H*2);
  u16* v_bf     = (u16*)take((size_t)R_REL*H*2);
  u16* ofW2b    = (u16*)take((size_t)N_OBJ*H*2);
  u16* vW2b     = (u16*)take((size_t)R_REL*H*2);
  const size_t mark = off;

  // union region: bf16 input copies (dead before chunk loop starts)
  u16* fmaps_bf = (u16*)(base + mark);
  u16* vr_bf    = fmaps_bf + (size_t)N_OBJ*OBJ_DIM;
  const size_t unionA = ((size_t)N_OBJ*OBJ_DIM + (size_t)R_REL*OBJ_DIM)*2;

  auto perbytes = [&](size_t rc)->size_t{
    return rc*((size_t)NODE*H*2     // hid (act aliases hid)
             + 2*1536*2             // msW bf16
             + 2*H*2                // X bf16
             + 16*64*4)             // cls partials
           + 1024;
  };
  int RC = 1024;
  while (RC > 64){
    size_t per = perbytes((size_t)RC);
    size_t need = mark + (per > unionA ? per : unionA);
    if (need <= ws_size) break;
    RC >>= 1;
  }
  const int NCH = R_REL / RC;
  const int M_c = RC*NODE;

  off = mark;
  u16* hid_c     = (u16*)take((size_t)M_c*H*2);
  u16* msW_bf    = (u16*)take((size_t)2*RC*1536*2);
  u16* X_bf      = (u16*)take((size_t)2*RC*H*2);
  float* clspart = (float*)take((size_t)16*RC*64*4);
  u16* act_c     = hid_c;   // STEP2 writes act over dead hidden

  argmax_copy_kernel<<<N_OBJ, 64, 0, stream>>>(obj_logits, out, preds);

  conv_f2b<<<2048, 256, 0, stream>>>(obj_fmaps, fmaps_bf, (long)N_OBJ*OBJ_DIM);
  conv_f2b<<<2048, 256, 0, stream>>>(vr, vr_bf, (long)R_REL*OBJ_DIM);
  conv_f2b<<<1024, 256, 0, stream>>>(obj_proj_w, opw_bf, (long)H*OBJ_DIM);
  conv_f2b<<<1024, 256, 0, stream>>>(rel_proj_w, rpw_bf, (long)H*OBJ_DIM);
  conv_f2b<<<256, 256, 0, stream>>>(e3u, e3u_bf, (long)H*H);
  conv_f2b<<<256, 256, 0, stream>>>(e5u, e5u_bf, (long)H*H);
  conv_ow<<<256, 256, 0, stream>>>(outw, ow1_bf, ow2_bf);
  conv_cls<<<2048, 256, 0, stream>>>(clsw, clsw_bf);
  wcat_kernel<<<768, 256, 0, stream>>>(e3w, e4w, e5w, wcat_bf);
  arel_kernel<<<204, 256, 0, stream>>>(preds, rel_inds, prior, Arel);

  // projections -> bf16 of/v
  { EpiArgs e{of_bf};
    gemm_bf16<<<dim3(H/128, N_OBJ/128), 256, 0, stream>>>(fmaps_bf, OBJ_DIM, opw_bf, OBJ_DIM, obj_proj_b, H, OBJ_DIM, e); }
  { EpiArgs e{v_bf};
    gemm_bf16<<<dim3(H/128, R_REL/128), 256, 0, stream>>>(vr_bf, OBJ_DIM, rpw_bf, OBJ_DIM, rel_proj_b, H, OBJ_DIM, e); }
  // loop-invariant out-layer inp-part projections (bf16)
  { EpiArgs e{ofW2b};
    gemm_bf16<<<dim3(H/128, N_OBJ/128), 256, 0, stream>>>(of_bf, H, ow2_bf, H, nullptr, H, H, e); }
  { EpiArgs e{vW2b};
    gemm_bf16<<<dim3(H/128, R_REL/128), 256, 0, stream>>>(v_bf, H, ow2_bf, H, nullptr, H, H, e); }

  float* rd = out + (size_t)N_OBJ*NCLS + N_OBJ;

  for (int c = 0; c < NCH; ++c){
    const int r0 = c*RC;
    FArgs fa;
    fa.hid = hid_c; fa.of = of_bf; fa.v = v_bf; fa.ri = rel_inds;
    fa.U3 = e3u_bf; fa.U5 = e5u_bf; fa.ow1 = ow1_bf;
    fa.u3b = e3ub; fa.u5b = e5ub; fa.b3 = e3wb; fa.b4 = e4wb; fa.b5 = e5wb;
    fa.outbias = outbias; fa.Arel = Arel; fa.msW = msW_bf;
    fa.ofW2b = ofW2b; fa.vW2b = vW2b; fa.act = act_c;
    fa.rbase = r0; fa.RCc = RC;

    const int nblk = M_c/64;

    // step 0
    mtop0_kernel<<<RC, 256, 0, stream>>>(of_bf, v_bf, rel_inds, Arel, X_bf, r0, RC);
    { EpiArgs e{msW_bf};
      gemm_bf16<<<dim3(1536/128, 2*RC/128), 256, 0, stream>>>(X_bf, H, wcat_bf, H, nullptr, 1536, H, e); }
    ggnn_step<0><<<nblk, 1024, 0, stream>>>(fa);
    // step 1
    mtopg_kernel<<<RC, 256, 0, stream>>>(hid_c, Arel, X_bf, r0, RC);
    { EpiArgs e{msW_bf};
      gemm_bf16<<<dim3(1536/128, 2*RC/128), 256, 0, stream>>>(X_bf, H, wcat_bf, H, nullptr, 1536, H, e); }
    ggnn_step<1><<<nblk, 1024, 0, stream>>>(fa);
    // step 2 (+ out-layer)
    mtopg_kernel<<<RC, 256, 0, stream>>>(hid_c, Arel, X_bf, r0, RC);
    { EpiArgs e{msW_bf};
      gemm_bf16<<<dim3(1536/128, 2*RC/128), 256, 0, stream>>>(X_bf, H, wcat_bf, H, nullptr, 1536, H, e); }
    ggnn_step<2><<<nblk, 1024, 0, stream>>>(fa);

    cls_gemm<<<dim3(RC/64, 16), 64, 0, stream>>>(act_c, clsw_bf, clspart, RC);
    cls_reduce<<<RC, 64, 0, stream>>>(clspart, clsb, rd, r0, RC);
  }
}

// Round 17
// 951.274 us; speedup vs baseline: 1.3937x; 1.3937x over previous
//
#include <hip/hip_runtime.h>
#include <math.h>

#define N_OBJ   2048
#define R_REL   1024
#define OBJ_DIM 4096
#define H       512
#define NREL    51
#define NCLS    151
#define NODE    53
#define CLS_K   (NODE*H)       /* 27136 */
#define AST     512

typedef unsigned short u16;
typedef unsigned int   u32;
typedef __attribute__((ext_vector_type(8))) short bf16x8;
typedef __attribute__((ext_vector_type(4))) float f32x4;
typedef __attribute__((ext_vector_type(4))) unsigned int u32x4;

__device__ __forceinline__ float sigmoidf_(float x){ return 1.0f/(1.0f+__expf(-x)); }
__device__ __forceinline__ float tanhf_(float x){ float e = __expf(2.0f*x); return 1.0f - 2.0f/(e+1.0f); }
__device__ __forceinline__ u16 f2bf(float x){
  unsigned u = __float_as_uint(x);
  unsigned r = (u + 0x7fffu + ((u>>16)&1u)) >> 16;
  return (u16)r;
}
__device__ __forceinline__ float bf2f(u16 h){ return __uint_as_float(((unsigned)h)<<16); }

#define GLL16(gp, lp) __builtin_amdgcn_global_load_lds( \
    (const __attribute__((address_space(1))) void*)(gp), \
    (__attribute__((address_space(3))) void*)(lp), 16, 0, 0)

struct EpiArgs {
  u16* cbf;     // bf16 output
};

// C[m,n] = sum_k A[m,k]*B[n,k] (+bias[n]) -> bf16 cbf. BM=BN=128, BK=32, 2-phase gll pipeline.
__global__ __launch_bounds__(256)
void gemm_bf16(const u16* __restrict__ A, int lda,
               const u16* __restrict__ B, int ldb,
               const float* __restrict__ bias,
               int ldc, int K, EpiArgs e)
{
  __shared__ __align__(16) u16 As[2][128*32];
  __shared__ __align__(16) u16 Bs[2][128*32];
  const int tid = threadIdx.x;
  const int l   = tid & 63;
  const int w   = tid >> 6;
  const int wm  = w >> 1, wn = w & 1;
  const int bm  = blockIdx.y*128, bn = blockIdx.x*128;
  const int lr  = l & 15, q = l >> 4;

  const int srow = w*32 + (l >> 2);
  const int scol = (l & 3)*8;
  const u16* gA = A + (size_t)(bm + srow)*lda + scol;
  const u16* gB = B + (size_t)(bn + srow)*ldb + scol;
  const size_t a16 = (size_t)16*lda, b16 = (size_t)16*ldb;

  f32x4 acc[4][4] = {};
  const int NT = K >> 5;

  {
    GLL16(gA,       &As[0][(w*32     )*32]);
    GLL16(gA + a16, &As[0][(w*32 + 16)*32]);
    GLL16(gB,       &Bs[0][(w*32     )*32]);
    GLL16(gB + b16, &Bs[0][(w*32 + 16)*32]);
  }
  __syncthreads();
  int cur = 0;
  for (int kt = 0; kt < NT; ++kt){
    if (kt + 1 < NT){
      const u16* ga = gA + (size_t)(kt+1)*32;
      const u16* gb = gB + (size_t)(kt+1)*32;
      const int nb = cur ^ 1;
      GLL16(ga,       &As[nb][(w*32     )*32]);
      GLL16(ga + a16, &As[nb][(w*32 + 16)*32]);
      GLL16(gb,       &Bs[nb][(w*32     )*32]);
      GLL16(gb + b16, &Bs[nb][(w*32 + 16)*32]);
    }
    bf16x8 af[4], bfr[4];
#pragma unroll
    for (int i = 0; i < 4; ++i)
      af[i] = *(const bf16x8*)&As[cur][(wm*64 + i*16 + lr)*32 + q*8];
#pragma unroll
    for (int i = 0; i < 4; ++i)
      bfr[i] = *(const bf16x8*)&Bs[cur][(wn*64 + i*16 + lr)*32 + q*8];
#pragma unroll
    for (int mi = 0; mi < 4; ++mi)
#pragma unroll
      for (int ni = 0; ni < 4; ++ni)
        acc[mi][ni] = __builtin_amdgcn_mfma_f32_16x16x32_bf16(af[mi], bfr[ni], acc[mi][ni], 0, 0, 0);
    __syncthreads();
    cur ^= 1;
  }

#pragma unroll
  for (int mi = 0; mi < 4; ++mi)
#pragma unroll
    for (int ni = 0; ni < 4; ++ni)
#pragma unroll
      for (int i = 0; i < 4; ++i){
        const int m = bm + wm*64 + mi*16 + q*4 + i;
        const int n = bn + wn*64 + ni*16 + lr;
        float val = acc[mi][ni][i];
        if (bias) val += bias[n];
        e.cbf[(size_t)m*ldc + n] = f2bf(val);
      }
}

// ---------------- fused GGNN GRU step (r15 structure + cross-phase B prefetch) ----------------
// 32-row flat tile, 512 threads = 8 waves (1 x 8). B staged PER-WAVE (private 2x4KB
// regions) with counted s_waitcnt vmcnt(N): zero barriers in the K-loop. NEW vs r15:
// each GEMM's first two B slabs are issued BEFORE the preceding epilogue (B source is
// phase-independent), so their L2 latency hides under epilogue VALU + phase barrier.
struct FArgs {
  u16* hid;              // [M][512] bf16, in-place updated
  const u16* of;         // [2048][512]
  const u16* v;          // [1024][512]
  const int* ri;
  const u16* U3;         // [512][512]
  const u16* U5;
  const u16* ow1;
  const float* u3b; const float* u5b;
  const float* b3; const float* b4; const float* b5;
  const float* outbias;
  const float* Arel;     // [R_REL][51]
  const u16* msW;        // [2*RC][1536] bf16
  const u16* ofW2b;      // [2048][512] bf16
  const u16* vW2b;       // [1024][512] bf16
  u16* act;              // [M][512] bf16 (STEP2 output; may alias hid)
  int rbase; int RCc;
};

#define SWZ(m_, n_) ((m_)*AST + ((((((n_)>>3)) ^ ((m_)&7))<<3) | ((n_)&7)))

template<int STEP>   // 0: gather-staged first step; 1: middle; 2: last + out-layer
__global__ __launch_bounds__(512)
void ggnn_step(FArgs a)
{
  __shared__ __align__(16) u16 Afl[32*AST];     // flat / h'  (32 KB)
  __shared__ __align__(16) u16 Rv[32*AST];      // rvf (32 KB)
  __shared__ __align__(16) u16 Bw[8*2*2048];    // per-wave B double buffers (64 KB)
  __shared__ __align__(16) u16 SmsW[4*1536];    // (12 KB)
  __shared__ float SArel[104];
  const int tid = threadIdx.x;
  const int w = tid >> 6, l = tid & 63;         // 8 waves
  const int lr = l & 15, q = l >> 4;
  const int gm0 = blockIdx.x * 32;
  const int rblk0 = gm0 / 53;
  const int rblk1 = (rblk0 + 1 < a.RCc) ? rblk0 + 1 : a.RCc - 1;
  u16* myB = &Bw[w*4096];

  // ---- stage A (flat) rows into LDS (pre-swizzled source cols); 4 rows per wave
#pragma unroll
  for (int j = 0; j < 4; ++j){
    const int row = j*8 + w;
    const int gm = gm0 + row;
    const u16* src;
    if (STEP == 0){
      const int r = gm/53, t = gm - r*53, gr = a.rbase + r;
      src = (t==0) ? a.of + (size_t)a.ri[gr*3+1]*512
          : (t==1) ? a.of + (size_t)a.ri[gr*3+2]*512
          :          a.v  + (size_t)gr*512;
    } else {
      src = a.hid + (size_t)gm*512;
    }
    GLL16(src + ((l ^ (row&7))<<3), &Afl[row*AST]);
  }
  // ---- stage this block's msW slice into LDS
  if (w < 4){
    const int rloc = w >> 1, half = w & 1;
    const int rg = rloc ? rblk1 : rblk0;
    const u16* srcw = a.msW + (size_t)(half ? (a.RCc + rg) : rg) * 1536;
#pragma unroll
    for (int j = 0; j < 3; ++j)
      GLL16(srcw + j*512 + l*8, &SmsW[(rloc*2+half)*1536 + j*512]);
  }
  // ---- stage Arel rows
  if (tid < 102){
    const int rloc = tid / 51, k = tid - rloc*51;
    const int rg = rloc ? rblk1 : rblk0;
    SArel[rloc*51 + k] = a.Arel[(size_t)(a.rbase + rg)*NREL + k];
  }

  f32x4 acc[2][4];
#define ZERO_ACC() { \
  _Pragma("unroll") for (int x_=0;x_<2;++x_) _Pragma("unroll") for (int y_=0;y_<4;++y_) acc[x_][y_] = (f32x4)0.0f; }

// wave-private B slab staging (4 GLL16 = 64 rows x 32 cols), slot-swizzled source
#define STAGE_W(Bp, buf_, kt_) { \
  _Pragma("unroll") for (int j_=0;j_<4;++j_){ \
    const int row_ = w*64 + j_*16 + (l>>2); \
    GLL16((Bp) + (size_t)row_*512 + (kt_)*32 + (((l&3) ^ ((row_>>1)&3))<<3), \
          &myB[(buf_)*2048 + j_*512]); } }

// preload first two slabs of the NEXT GEMM's B (issued before the phase barrier;
// the barrier drains vmcnt so the in-body vmcnt(4) waits are trivially satisfied)
#define PRELOAD(Bp) { STAGE_W(Bp, 0, 0); STAGE_W(Bp, 1, 1); }

// barrier-free pipelined K-loop body: depth-2 prefetch, counted vmcnt (4 loads/slab).
// Assumes slabs 0 and 1 already staged (by PRELOAD) and vmcnt drained by a barrier.
#define RUN_BODY(Ap, Bp) { \
  _Pragma("unroll 1") \
  for (int kt = 0; kt < 16; ++kt){ \
    if (kt < 15) { asm volatile("s_waitcnt vmcnt(4)" ::: "memory"); } \
    else         { asm volatile("s_waitcnt vmcnt(0)" ::: "memory"); } \
    __builtin_amdgcn_sched_barrier(0); \
    bf16x8 af_[2], bf_[4]; \
    _Pragma("unroll") for (int mi_=0;mi_<2;++mi_){ \
      const int row_ = mi_*16 + lr; \
      af_[mi_] = *(const bf16x8*)&(Ap)[row_*AST + (((kt*4+q) ^ (row_&7))<<3)]; } \
    _Pragma("unroll") for (int ni_=0;ni_<4;++ni_){ \
      const int lrow_ = ni_*16 + lr; \
      bf_[ni_] = *(const bf16x8*)&myB[(kt&1)*2048 + lrow_*32 + ((q ^ ((lrow_>>1)&3))<<3)]; } \
    asm volatile("s_waitcnt lgkmcnt(0)" ::: "memory"); \
    __builtin_amdgcn_sched_barrier(0); \
    if (kt + 2 < 16) STAGE_W(Bp, kt&1, kt+2); \
    _Pragma("unroll") for (int mi_=0;mi_<2;++mi_) \
      _Pragma("unroll") for (int ni_=0;ni_<4;++ni_) \
        acc[mi_][ni_] = __builtin_amdgcn_mfma_f32_16x16x32_bf16(af_[mi_], bf_[ni_], acc[mi_][ni_], 0, 0, 0); \
  } }

  // ---- GEMM1: flat @ U3^T (B preloaded alongside A/msW staging; barrier drains all)
  PRELOAD(a.U3);
  __syncthreads();
  ZERO_ACC();
  RUN_BODY(Afl, a.U3);

  // prefetch GEMM2's first B slabs; latency hides under epilogue-1 + barrier
  PRELOAD(a.U5);

  // ---- epilogue 1: z -> packed regs; rvf -> Rv (Afl untouched); no VMEM here
  float vb3[4], vb4[4], vu3[4];
#pragma unroll
  for (int ni=0;ni<4;++ni){
    const int n = w*64 + ni*16 + lr;
    vb3[ni]=a.b3[n]; vb4[ni]=a.b4[n]; vu3[ni]=a.u3b[n];
  }
  u32 z_pk[2][2][4] = {};
#pragma unroll
  for (int mi=0;mi<2;++mi)
#pragma unroll
   for (int i=0;i<4;++i){
    const int m = mi*16 + q*4 + i;
    const int gm = gm0 + m;
    const int r = gm/53, t = gm - r*53;
    const int rloc = r - rblk0;
    const float aA = (t<2) ? 1.0f : SArel[rloc*51 + (t-2)];
    const u16* mrow = &SmsW[(rloc*2 + ((t<2)?0:1))*1536];
#pragma unroll
    for (int ni=0;ni<4;++ni){
      const int n = w*64 + ni*16 + lr;
      const float val = acc[mi][ni][i] + vu3[ni];
      const float z  = sigmoidf_(fmaf(aA, bf2f(mrow[n]),     vb3[ni]) + val);
      const float rv = sigmoidf_(fmaf(aA, bf2f(mrow[512+n]), vb4[ni]) + val);
      const int sidx = SWZ(m, n);
      const float fl = bf2f(Afl[sidx]);
      z_pk[mi][i>>1][ni] |= ((u32)f2bf(z))  << ((i&1)*16);
      Rv[sidx] = f2bf(rv*fl);
    }
   }
  __syncthreads();   // Rv complete; also drains the U5 preload

  // ---- GEMM2: rvf @ U5^T
  ZERO_ACC();
  RUN_BODY(Rv, a.U5);

  if (STEP == 2) PRELOAD(a.ow1);   // prefetch GEMM3's B under the blend epilogue

  float vu5[4], vb5[4];
#pragma unroll
  for (int ni=0;ni<4;++ni){
    const int n = w*64 + ni*16 + lr;
    vu5[ni]=a.u5b[n]; vb5[ni]=a.b5[n];
  }
#pragma unroll
  for (int mi=0;mi<2;++mi)
#pragma unroll
   for (int i=0;i<4;++i){
    const int m = mi*16 + q*4 + i;
    const int gm = gm0 + m;
    const int r = gm/53, t = gm - r*53;
    const int rloc = r - rblk0;
    const float aA = (t<2) ? 1.0f : SArel[rloc*51 + (t-2)];
    const u16* mrow = &SmsW[(rloc*2 + ((t<2)?0:1))*1536];
#pragma unroll
    for (int ni=0;ni<4;++ni){
      const int n = w*64 + ni*16 + lr;
      const float val = acc[mi][ni][i] + vu5[ni];
      const float hv = tanhf_(fmaf(aA, bf2f(mrow[1024+n]), vb5[ni]) + val);
      const float z  = bf2f((u16)(z_pk[mi][i>>1][ni] >> ((i&1)*16)));
      const int sidx = SWZ(m, n);
      const float fl = bf2f(Afl[sidx]);    // flat still intact
      Afl[sidx] = f2bf((1.0f - z)*fl + z*hv);
    }
   }
  __syncthreads();   // h' complete in Afl; drains ow1 preload (STEP2)

  if (STEP < 2){
#pragma unroll
    for (int it = 0; it < 4; ++it){
      const int s = it*512 + tid;
      const int row = s >> 6, cc = s & 63;
      const u32x4 v4 = *(const u32x4*)&Afl[row*AST + ((cc ^ (row&7))<<3)];
      __builtin_nontemporal_store(v4, (u32x4*)&a.hid[(size_t)(gm0+row)*512 + (cc<<3)]);
    }
  } else {
    // ---- GEMM3: out = relu(h' @ ow1^T + gather + outbias) -> Rv
    ZERO_ACC();
    RUN_BODY(Afl, a.ow1);
    float vob[4];
#pragma unroll
    for (int ni=0;ni<4;++ni) vob[ni] = a.outbias[w*64 + ni*16 + lr];
#pragma unroll
    for (int mi=0;mi<2;++mi)
#pragma unroll
     for (int i=0;i<4;++i){
      const int m = mi*16 + q*4 + i;
      const int gm = gm0 + m;
      const int r = gm/53, t = gm - r*53, gr = a.rbase + r;
      const u16* g = (t==0) ? a.ofW2b + (size_t)a.ri[gr*3+1]*512
                   : (t==1) ? a.ofW2b + (size_t)a.ri[gr*3+2]*512
                   :          a.vW2b  + (size_t)gr*512;
#pragma unroll
      for (int ni=0;ni<4;++ni){
        const int n = w*64 + ni*16 + lr;
        const float val = acc[mi][ni][i] + vob[ni] + bf2f(__builtin_nontemporal_load(&g[n]));
        Rv[SWZ(m, n)] = f2bf(fmaxf(val, 0.0f));
      }
     }
    __syncthreads();
#pragma unroll
    for (int it = 0; it < 4; ++it){
      const int s = it*512 + tid;
      const int row = s >> 6, cc = s & 63;
      const u32x4 v4 = *(const u32x4*)&Rv[row*AST + ((cc ^ (row&7))<<3)];
      __builtin_nontemporal_store(v4, (u32x4*)&a.act[(size_t)(gm0+row)*512 + (cc<<3)]);
    }
  }
#undef RUN_BODY
#undef PRELOAD
#undef STAGE_W
#undef ZERO_ACC
}

// classifier split-K
__global__ __launch_bounds__(64)
void cls_gemm(const u16* __restrict__ A, const u16* __restrict__ B,
              float* __restrict__ part, int RC)
{
  const int bm = blockIdx.x*64;
  const int kz = blockIdx.y;
  const int l  = threadIdx.x;
  const int lr = l & 15, q = l >> 4;
  f32x4 acc[4][4] = {};
  const size_t kbase = (size_t)kz*1696 + q*8;
  for (int kt = 0; kt < 53; ++kt){
    const size_t ko = kbase + (size_t)kt*32;
    bf16x8 af[4], bfr[4];
#pragma unroll
    for (int i = 0; i < 4; ++i)
      af[i] = *(const bf16x8*)&A[(size_t)(bm + i*16 + lr)*CLS_K + ko];
#pragma unroll
    for (int i = 0; i < 4; ++i)
      bfr[i] = *(const bf16x8*)&B[(size_t)(i*16 + lr)*CLS_K + ko];
#pragma unroll
    for (int mi = 0; mi < 4; ++mi)
#pragma unroll
      for (int ni = 0; ni < 4; ++ni)
        acc[mi][ni] = __builtin_amdgcn_mfma_f32_16x16x32_bf16(af[mi], bfr[ni], acc[mi][ni], 0, 0, 0);
  }
#pragma unroll
  for (int mi = 0; mi < 4; ++mi)
#pragma unroll
    for (int ni = 0; ni < 4; ++ni)
#pragma unroll
      for (int i = 0; i < 4; ++i){
        int m = bm + mi*16 + q*4 + i;
        int n = ni*16 + lr;
        part[((size_t)kz*RC + m)*64 + n] = acc[mi][ni][i];
      }
}

__global__ void cls_reduce(const float* __restrict__ part, const float* __restrict__ clsb,
                           float* __restrict__ rd, int r0, int RC)
{
  const int m = blockIdx.x;
  const int c = threadIdx.x;
  if (c < NREL){
    float s = clsb[c];
    for (int kz = 0; kz < 16; ++kz) s += part[((size_t)kz*RC + m)*64 + c];
    rd[(size_t)(r0 + m)*NREL + c] = s;
  }
}

__global__ void argmax_copy_kernel(const float* __restrict__ logits, float* __restrict__ out, int* __restrict__ preds)
{
  const int i = blockIdx.x;
  const int lane = threadIdx.x; // 64
  for (int c = lane; c < NCLS; c += 64)
    out[(size_t)i*NCLS + c] = logits[(size_t)i*NCLS + c];
  float bv = -INFINITY; int bi = 0x7fffffff;
  for (int c = 1 + lane; c < NCLS; c += 64){
    float x = logits[(size_t)i*NCLS + c];
    if (x > bv){ bv = x; bi = c; }
  }
  for (int off = 32; off; off >>= 1){
    float ov = __shfl_down(bv, off);
    int   oi = __shfl_down(bi, off);
    if (ov > bv || (ov == bv && oi < bi)){ bv = ov; bi = oi; }
  }
  if (lane == 0){
    preds[i] = bi;
    out[(size_t)N_OBJ*NCLS + i] = (float)bi;
  }
}

__global__ void conv_f2b(const float* __restrict__ s, u16* __restrict__ d, long n)
{
  for (long i = (long)blockIdx.x*blockDim.x + threadIdx.x; i < n; i += (long)gridDim.x*blockDim.x)
    d[i] = f2bf(s[i]);
}

__global__ void conv_ow(const float* __restrict__ src, u16* __restrict__ d1, u16* __restrict__ d2)
{
  for (int i = blockIdx.x*blockDim.x + threadIdx.x; i < 512*512; i += gridDim.x*blockDim.x){
    int r = i >> 9, c = i & 511;
    d1[i] = f2bf(src[(size_t)r*1024 + c]);
    d2[i] = f2bf(src[(size_t)r*1024 + 512 + c]);
  }
}

__global__ void conv_cls(const float* __restrict__ src, u16* __restrict__ dst)
{
  const long total = 64L*CLS_K;
  for (long i = (long)blockIdx.x*blockDim.x + threadIdx.x; i < total; i += (long)gridDim.x*blockDim.x){
    long r = i / CLS_K, c = i - r*CLS_K;
    dst[i] = (r < NREL) ? f2bf(src[(size_t)r*CLS_K + c]) : (u16)0;
  }
}

__global__ void wcat_kernel(const float* __restrict__ e3w, const float* __restrict__ e4w,
                            const float* __restrict__ e5w, u16* __restrict__ Wcat)
{
  const int total = 1536*512;
  for (int i = blockIdx.x*blockDim.x + threadIdx.x; i < total; i += gridDim.x*blockDim.x){
    int j = i >> 9, k = i & 511;
    int w = j >> 9, n = j & 511;
    const float* Wp = (w == 0) ? e3w : (w == 1) ? e4w : e5w;
    Wcat[i] = f2bf(Wp[(size_t)n*1024 + k] + Wp[(size_t)n*1024 + 512 + k]);
  }
}

__global__ void arel_kernel(const int* __restrict__ preds, const int* __restrict__ ri,
                            const float* __restrict__ prior, float* __restrict__ Arel)
{
  const int total = R_REL*NREL;
  for (int i = blockIdx.x*blockDim.x + threadIdx.x; i < total; i += gridDim.x*blockDim.x){
    int r = i/NREL, k = i - r*NREL;
    int sp = preds[ri[r*3+1]];
    int op = preds[ri[r*3+2]];
    Arel[i] = prior[((size_t)sp*NCLS + op)*NREL + k];
  }
}

// step-0 X: m_top = (sum_k A[r,k]) * v[r]; s = of[si]+of[oi]
__global__ void mtop0_kernel(const u16* __restrict__ of_bf, const u16* __restrict__ v_bf,
                             const int* __restrict__ ri, const float* __restrict__ Arel,
                             u16* __restrict__ X, int rbase, int RC)
{
  const int r = blockIdx.x;
  const int gr = rbase + r;
  float sA = 0.f;
  for (int k = 0; k < NREL; ++k) sA += Arel[(size_t)gr*NREL + k];
  const int si = ri[gr*3+1], oi = ri[gr*3+2];
  for (int h = threadIdx.x; h < H; h += blockDim.x){
    X[(size_t)r*H + h] = f2bf(sA * bf2f(v_bf[(size_t)gr*H + h]));
    X[(size_t)(RC + r)*H + h] = f2bf(bf2f(of_bf[(size_t)si*H + h]) + bf2f(of_bf[(size_t)oi*H + h]));
  }
}

// general X from bf16 hidden
__global__ void mtopg_kernel(const u16* __restrict__ hidden, const float* __restrict__ Arel,
                             u16* __restrict__ X, int rbase, int RC)
{
  const int r = blockIdx.x;
  for (int h = threadIdx.x; h < H; h += blockDim.x){
    const u16* basep = hidden + ((size_t)r*NODE + 2)*H + h;
    float acc = 0.f;
    for (int k = 0; k < NREL; ++k)
      acc = fmaf(Arel[(size_t)(rbase+r)*NREL + k], bf2f(basep[(size_t)k*H]), acc);
    X[(size_t)r*H + h] = f2bf(acc);
    X[(size_t)(RC + r)*H + h] = f2bf(bf2f(hidden[(size_t)(r*NODE)*H + h]) + bf2f(hidden[(size_t)(r*NODE+1)*H + h]));
  }
}

extern "C" void kernel_launch(void* const* d_in, const int* in_sizes, int n_in,
                              void* d_out, int out_size, void* d_ws, size_t ws_size,
                              hipStream_t stream)
{
  const float* obj_fmaps = (const float*)d_in[0];
  const float* obj_logits= (const float*)d_in[1];
  const int*   rel_inds  = (const int*)d_in[2];
  const float* vr        = (const float*)d_in[3];
  const float* prior     = (const float*)d_in[4];
  const float* obj_proj_w= (const float*)d_in[5];
  const float* obj_proj_b= (const float*)d_in[6];
  const float* rel_proj_w= (const float*)d_in[7];
  const float* rel_proj_b= (const float*)d_in[8];
  const float* e3w =(const float*)d_in[9];
  const float* e3wb=(const float*)d_in[10];
  const float* e3u =(const float*)d_in[11];
  const float* e3ub=(const float*)d_in[12];
  const float* e4w =(const float*)d_in[13];
  const float* e4wb=(const float*)d_in[14];
  const float* e5w =(const float*)d_in[15];
  const float* e5wb=(const float*)d_in[16];
  const float* e5u =(const float*)d_in[17];
  const float* e5ub=(const float*)d_in[18];
  const float* outw=(const float*)d_in[19];
  const float* outbias=(const float*)d_in[20];
  const float* clsw=(const float*)d_in[21];
  const float* clsb=(const float*)d_in[22];
  float* out = (float*)d_out;
  (void)in_sizes; (void)n_in; (void)out_size;

  char* base = (char*)d_ws;
  size_t off = 0;
  auto take = [&](size_t bytes)->void*{
    void* p = base + off; off = (off + bytes + 63) & ~(size_t)63; return p;
  };
  // persistent (~21 MB)
  float* Arel   = (float*)take((size_t)R_REL*NREL*4);
  int*   preds  = (int*)take((size_t)N_OBJ*4);
  u16* opw_bf   = (u16*)take((size_t)H*OBJ_DIM*2);
  u16* rpw_bf   = (u16*)take((size_t)H*OBJ_DIM*2);
  u16* e3u_bf   = (u16*)take((size_t)H*H*2);
  u16* e5u_bf   = (u16*)take((size_t)H*H*2);
  u16* ow1_bf   = (u16*)take((size_t)H*H*2);
  u16* ow2_bf   = (u16*)take((size_t)H*H*2);
  u16* wcat_bf  = (u16*)take((size_t)1536*H*2);
  u16* clsw_bf  = (u16*)take((size_t)64*CLS_K*2);
  u16* of_bf    = (u16*)take((size_t)N_OBJ*H*2);
  u16* v_bf     = (u16*)take((size_t)R_REL*H*2);
  u16* ofW2b    = (u16*)take((size_t)N_OBJ*H*2);
  u16* vW2b     = (u16*)take((size_t)R_REL*H*2);
  const size_t mark = off;

  // union region: bf16 input copies (dead before chunk loop starts)
  u16* fmaps_bf = (u16*)(base + mark);
  u16* vr_bf    = fmaps_bf + (size_t)N_OBJ*OBJ_DIM;
  const size_t unionA = ((size_t)N_OBJ*OBJ_DIM + (size_t)R_REL*OBJ_DIM)*2;

  auto perbytes = [&](size_t rc)->size_t{
    return rc*((size_t)NODE*H*2     // hid (act aliases hid)
             + 2*1536*2             // msW bf16
             + 2*H*2                // X bf16
             + 16*64*4)             // cls partials
           + 1024;
  };
  int RC = 1024;
  while (RC > 64){
    size_t per = perbytes((size_t)RC);
    size_t need = mark + (per > unionA ? per : unionA);
    if (need <= ws_size) break;
    RC >>= 1;
  }
  const int NCH = R_REL / RC;
  const int M_c = RC*NODE;

  off = mark;
  u16* hid_c     = (u16*)take((size_t)M_c*H*2);
  u16* msW_bf    = (u16*)take((size_t)2*RC*1536*2);
  u16* X_bf      = (u16*)take((size_t)2*RC*H*2);
  float* clspart = (float*)take((size_t)16*RC*64*4);
  u16* act_c     = hid_c;   // STEP2 writes act over dead hidden

  argmax_copy_kernel<<<N_OBJ, 64, 0, stream>>>(obj_logits, out, preds);

  conv_f2b<<<2048, 256, 0, stream>>>(obj_fmaps, fmaps_bf, (long)N_OBJ*OBJ_DIM);
  conv_f2b<<<2048, 256, 0, stream>>>(vr, vr_bf, (long)R_REL*OBJ_DIM);
  conv_f2b<<<1024, 256, 0, stream>>>(obj_proj_w, opw_bf, (long)H*OBJ_DIM);
  conv_f2b<<<1024, 256, 0, stream>>>(rel_proj_w, rpw_bf, (long)H*OBJ_DIM);
  conv_f2b<<<256, 256, 0, stream>>>(e3u, e3u_bf, (long)H*H);
  conv_f2b<<<256, 256, 0, stream>>>(e5u, e5u_bf, (long)H*H);
  conv_ow<<<256, 256, 0, stream>>>(outw, ow1_bf, ow2_bf);
  conv_cls<<<2048, 256, 0, stream>>>(clsw, clsw_bf);
  wcat_kernel<<<768, 256, 0, stream>>>(e3w, e4w, e5w, wcat_bf);
  arel_kernel<<<204, 256, 0, stream>>>(preds, rel_inds, prior, Arel);

  // projections -> bf16 of/v
  { EpiArgs e{of_bf};
    gemm_bf16<<<dim3(H/128, N_OBJ/128), 256, 0, stream>>>(fmaps_bf, OBJ_DIM, opw_bf, OBJ_DIM, obj_proj_b, H, OBJ_DIM, e); }
  { EpiArgs e{v_bf};
    gemm_bf16<<<dim3(H/128, R_REL/128), 256, 0, stream>>>(vr_bf, OBJ_DIM, rpw_bf, OBJ_DIM, rel_proj_b, H, OBJ_DIM, e); }
  // loop-invariant out-layer inp-part projections (bf16)
  { EpiArgs e{ofW2b};
    gemm_bf16<<<dim3(H/128, N_OBJ/128), 256, 0, stream>>>(of_bf, H, ow2_bf, H, nullptr, H, H, e); }
  { EpiArgs e{vW2b};
    gemm_bf16<<<dim3(H/128, R_REL/128), 256, 0, stream>>>(v_bf, H, ow2_bf, H, nullptr, H, H, e); }

  float* rd = out + (size_t)N_OBJ*NCLS + N_OBJ;

  for (int c = 0; c < NCH; ++c){
    const int r0 = c*RC;
    FArgs fa;
    fa.hid = hid_c; fa.of = of_bf; fa.v = v_bf; fa.ri = rel_inds;
    fa.U3 = e3u_bf; fa.U5 = e5u_bf; fa.ow1 = ow1_bf;
    fa.u3b = e3ub; fa.u5b = e5ub; fa.b3 = e3wb; fa.b4 = e4wb; fa.b5 = e5wb;
    fa.outbias = outbias; fa.Arel = Arel; fa.msW = msW_bf;
    fa.ofW2b = ofW2b; fa.vW2b = vW2b; fa.act = act_c;
    fa.rbase = r0; fa.RCc = RC;

    const int nblk = M_c/32;

    // step 0
    mtop0_kernel<<<RC, 256, 0, stream>>>(of_bf, v_bf, rel_inds, Arel, X_bf, r0, RC);
    { EpiArgs e{msW_bf};
      gemm_bf16<<<dim3(1536/128, 2*RC/128), 256, 0, stream>>>(X_bf, H, wcat_bf, H, nullptr, 1536, H, e); }
    ggnn_step<0><<<nblk, 512, 0, stream>>>(fa);
    // step 1
    mtopg_kernel<<<RC, 256, 0, stream>>>(hid_c, Arel, X_bf, r0, RC);
    { EpiArgs e{msW_bf};
      gemm_bf16<<<dim3(1536/128, 2*RC/128), 256, 0, stream>>>(X_bf, H, wcat_bf, H, nullptr, 1536, H, e); }
    ggnn_step<1><<<nblk, 512, 0, stream>>>(fa);
    // step 2 (+ out-layer)
    mtopg_kernel<<<RC, 256, 0, stream>>>(hid_c, Arel, X_bf, r0, RC);
    { EpiArgs e{msW_bf};
      gemm_bf16<<<dim3(1536/128, 2*RC/128), 256, 0, stream>>>(X_bf, H, wcat_bf, H, nullptr, 1536, H, e); }
    ggnn_step<2><<<nblk, 512, 0, stream>>>(fa);

    cls_gemm<<<dim3(RC/64, 16), 64, 0, stream>>>(act_c, clsw_bf, clspart, RC);
    cls_reduce<<<RC, 64, 0, stream>>>(clspart, clsb, rd, r0, RC);
  }
}